// Round 18
// baseline (20585.478 us; speedup 1.0000x reference)
//
#include <hip/hip_runtime.h>

// ---- geometry ----
#define PLANE28   784                  // 28*28
#define NPLANE28  (16*64*PLANE28)      // 802816  [16,64,28,28]
#define NPLANE56  (16*64*56*56)        // 3211264 [16,64,56,56]
#define C1T_ROWS  61
#define C1T_S     44                   // padded row stride (4*44 % 32 == 16 -> 2-way max)
#define C1T_LOG   (C1T_ROWS*37)        // 2257 logical words
#define PPLANE    900                  // padded 30*30
#define NPPLANE   (16*64*PPLANE)       // 921600

// FROZEN SEMANTICS (validated rounds 7-11,15-17, absmax=0):
//  - conv reductions: per-ic subtotal. sub = fmaf chain over (ky outer, kx inner),
//    OOB as zero-tap fmaf no-op (zero-halo padded layout is bit-identical);
//    acc = acc + sub in ic order.
//  - membrane: m = mem*0.8f; m = m + conv; [m = m + resid;]  (contract OFF)
//  - fc: 8 x 512-term sequential fmaf chains, subtotals added in order; o = acc + b.
//  - pool sums are exact small integers (order-free), divided by 9.0f / 49.0f.
// LESSON (r14): never fully unroll a pipelined load loop (hoist->spill).
// LESSON (r15): mask removal + prefetch depth NEUTRAL.
// LESSON (r16/r17): anything that drops blocks/CU below 4 loses; LDS tap-share
// at 2/CU loses. Theory now: s_load weight misses (36KB set vs 16KB K$) are
// the stall -> v9 stages weights in LDS (uniform ds_read broadcast).

// ---------------- weight transposes (once per launch) -----------------------
__global__ __launch_bounds__(256) void transpose_w1(const float* __restrict__ w,
                                                    float* __restrict__ wt) {
    int i = blockIdx.x * 256 + threadIdx.x;
    if (i >= 64 * 20 * 49) return;
    int oc = i / 980;
    int r  = i % 980;
    int ic = r / 49;
    int ky = (r % 49) / 7;
    int kx = r % 7;
    wt[((ic * 7 + ky) * 7 + kx) * 64 + oc] = w[i];
}

// [8][64oc][64ic][3ky][3kx] -> [8][16 ocg][64 ic][9][4 oc]   (v6 and v9)
__global__ __launch_bounds__(256) void transpose_wb4(const float* __restrict__ w,
                                                     float* __restrict__ wt) {
    int i = blockIdx.x * 256 + threadIdx.x;
    if (i >= 8 * 64 * 64 * 9) return;
    int l  = i / 36864;
    int r  = i % 36864;
    int oc = r / 576;
    int r2 = r % 576;
    int ic = r2 / 9;
    int t9 = r2 % 9;
    wt[l * 36864 + (oc >> 2) * 2304 + ic * 36 + t9 * 4 + (oc & 3)] = w[i];
}

// ---------------- conv1 7x7 s2 p3 (20->64) + membrane, stride-44 LDS --------
__global__ __launch_bounds__(256) void conv1_t4(
    const float* __restrict__ x,    // [16,8,20,112,112]
    const float* __restrict__ wt,   // [20][7][7][64]
    float* __restrict__ c_mem,      // [16,64,56,56]
    int t)
{
    __shared__ float tile[C1T_ROWS * C1T_S];   // 61 x 44 = 2684 floats
    const int tid = threadIdx.x;
    const int bx  = blockIdx.x >> 1;
    const int yh  = blockIdx.x & 1;
    const int oc0 = blockIdx.y * 8;
    const int n   = blockIdx.z;
    const int tx  = tid & 15;
    const int ty  = tid >> 4;            // active ty<14
    const float* xin = x + ((size_t)(n * 8 + t)) * 20 * 12544;
    const int cbase = 32 * bx - 3;
    const int row0  = 56 * yh - 3;

    float acc[8][2];
#pragma unroll
    for (int o = 0; o < 8; ++o) { acc[o][0] = 0.f; acc[o][1] = 0.f; }

#pragma unroll
    for (int k = 0; k < 9; ++k) {
        int idx = tid + k * 256;
        if (idx < C1T_LOG) {
            int r = idx / 37, c = idx - r * 37;
            int ri = row0 + r, ci = cbase + c;
            float v = 0.f;
            if ((unsigned)ri < 112u && (unsigned)ci < 112u) v = xin[ri * 112 + ci];
            int cpos = (c >> 1) + ((c & 1) ? 19 : 0);
            tile[r * C1T_S + cpos] = v;
        }
    }

    for (int ic = 0; ic < 20; ++ic) {
        __syncthreads();
        float pre[9];
        if (ic + 1 < 20) {
            const float* src = xin + (ic + 1) * 12544;
#pragma unroll
            for (int k = 0; k < 9; ++k) {
                int idx = tid + k * 256;
                float v = 0.f;
                if (idx < C1T_LOG) {
                    int r = idx / 37, c = idx - r * 37;
                    int ri = row0 + r, ci = cbase + c;
                    if ((unsigned)ri < 112u && (unsigned)ci < 112u) v = src[ri * 112 + ci];
                }
                pre[k] = v;
            }
        }
        if (ty < 14) {
            float sub[8][2];
#pragma unroll
            for (int o = 0; o < 8; ++o) { sub[o][0] = 0.f; sub[o][1] = 0.f; }
            const float* wic = wt + ic * (49 * 64) + oc0;
#pragma unroll
            for (int ky = 0; ky < 7; ++ky) {     // ky OUTER (frozen order)
#pragma unroll
                for (int kx = 0; kx < 7; ++kx) { // kx INNER
                    const int koff = (kx >> 1) + ((kx & 1) ? 19 : 0);
                    const float* wp = wic + (ky * 7 + kx) * 64;
                    const float v0 = tile[(4 * ty + 0 + ky) * C1T_S + tx + koff];
                    const float v1 = tile[(4 * ty + 2 + ky) * C1T_S + tx + koff];
#pragma unroll
                    for (int o = 0; o < 8; ++o) {
                        const float wv = wp[o];
                        sub[o][0] = fmaf(v0, wv, sub[o][0]);
                        sub[o][1] = fmaf(v1, wv, sub[o][1]);
                    }
                }
            }
#pragma unroll
            for (int o = 0; o < 8; ++o) {
                acc[o][0] = acc[o][0] + sub[o][0];
                acc[o][1] = acc[o][1] + sub[o][1];
            }
        }
        __syncthreads();
        if (ic + 1 < 20) {
#pragma unroll
            for (int k = 0; k < 9; ++k) {
                int idx = tid + k * 256;
                if (idx < C1T_LOG) {
                    int r = idx / 37, c = idx - r * 37;
                    int cpos = (c >> 1) + ((c & 1) ? 19 : 0);
                    tile[r * C1T_S + cpos] = pre[k];
                }
            }
        }
    }

    const int xg = 16 * bx + tx;
    if (ty < 14 && xg < 56) {
#pragma clang fp contract(off)
#pragma unroll
        for (int o = 0; o < 8; ++o) {
#pragma unroll
            for (int d = 0; d < 2; ++d) {
                const int yg = 28 * yh + 2 * ty + d;
                size_t idx = (((size_t)n * 64 + oc0 + o) * 56 + yg) * 56 + xg;
                float m = c_mem[idx] * 0.8f;
                m = m + acc[o][d];
                c_mem[idx] = m;
            }
        }
    }
}

// ---------------- avg_pool + padded-layout write ----------------------------
__global__ __launch_bounds__(256) void pool1_p2(const float* __restrict__ c_mem,
                                                float* __restrict__ cur,
                                                float* __restrict__ pcur) {
    int i = blockIdx.x * 256 + threadIdx.x;
    if (i >= NPLANE28) return;
    int xx = i % 28, yy = (i / 28) % 28;
    int p  = i / PLANE28;
    const float* src = c_mem + (size_t)p * 3136;
    float s = 0.f;
    for (int ky = 0; ky < 3; ++ky) {
        int iy = 2 * yy - 1 + ky;
        if ((unsigned)iy >= 56u) continue;
        for (int kx = 0; kx < 3; ++kx) {
            int ix = 2 * xx - 1 + kx;
            if ((unsigned)ix < 56u)
                s += (src[iy * 56 + ix] > 0.5f) ? 1.f : 0.f;
        }
    }
    float v = s / 9.0f;
    cur[i] = v;
    pcur[(size_t)p * PPLANE + (yy + 1) * 30 + (xx + 1)] = v;
}

// ---------------- common tap/comp macros (frozen chain) ---------------------
#define BC_LD9(V, IC)                                        \
    {                                                        \
        const float* q = p + (size_t)(IC) * PPLANE;          \
        V[0] = q[0];  V[1] = q[1];  V[2] = q[2];             \
        V[3] = q[30]; V[4] = q[31]; V[5] = q[32];            \
        V[6] = q[60]; V[7] = q[61]; V[8] = q[62];            \
    }

#define BC_COMP_W(V, IC, WBASE)                              \
    {                                                        \
        const float* wic = (WBASE) + (IC) * 36;              \
        float sub[4];                                        \
        sub[0] = 0.f; sub[1] = 0.f; sub[2] = 0.f; sub[3] = 0.f; \
        _Pragma("unroll")                                    \
        for (int t9 = 0; t9 < 9; ++t9) {                     \
            const float* wp = wic + t9 * 4;                  \
            _Pragma("unroll")                                \
            for (int o = 0; o < 4; ++o)                      \
                sub[o] = fmaf(V[t9], wp[o], sub[o]);         \
        }                                                    \
        _Pragma("unroll")                                    \
        for (int o = 0; o < 4; ++o) acc[o] = acc[o] + sub[o];\
    }

// ---------------- bconv v6 (r15 proven: global s_load weights) --------------
template <bool HASRES, bool WRITESOUT>
__global__ __launch_bounds__(256, 4) void bconv_v6(
    const float* __restrict__ pin,    // padded [16][64][30][30]
    const float* __restrict__ wt,     // [16 ocg][64 ic][9][4]
    float* __restrict__ mem,
    float* __restrict__ sout,
    const float* __restrict__ resid,
    float* __restrict__ psout)
{
    const int tid = threadIdx.x;
    if (tid >= 196) return;
    const int yq  = blockIdx.x;
    const int ocg = blockIdx.y;       // 0..15
    const int oc0 = ocg * 4;
    const int n   = blockIdx.z;
    const int xx  = tid % 28;
    const int rl  = tid / 28;
    const int yy  = yq * 7 + rl;

    const float* p = pin + (size_t)n * 64 * PPLANE + yy * 30 + xx;
    const float* wblk = wt + ocg * 2304;

    float acc[4];
#pragma unroll
    for (int o = 0; o < 4; ++o) acc[o] = 0.f;

    float va[9], vb[9], vc[9], vd[9];
    BC_LD9(va, 0)
    BC_LD9(vb, 1)
#pragma clang loop unroll(disable)
    for (int ic = 0; ic < 64; ic += 4) {
        BC_LD9(vc, ic + 2)
        BC_COMP_W(va, ic, wblk)
        BC_LD9(vd, ic + 3)
        BC_COMP_W(vb, ic + 1, wblk)
        if (ic + 4 < 64) BC_LD9(va, ic + 4)
        BC_COMP_W(vc, ic + 2, wblk)
        if (ic + 5 < 64) BC_LD9(vb, ic + 5)
        BC_COMP_W(vd, ic + 3, wblk)
    }

    {
#pragma clang fp contract(off)
#pragma unroll
        for (int o = 0; o < 4; ++o) {
            size_t idx = (((size_t)n * 64 + oc0 + o) * 28 + yy) * 28 + xx;
            float m = mem[idx] * 0.8f;
            m = m + acc[o];
            if (HASRES) m = m + resid[idx];
            mem[idx] = m;
            float sp = (m > 0.5f) ? 1.f : 0.f;
            psout[((size_t)n * 64 + oc0 + o) * PPLANE + (yy + 1) * 30 + (xx + 1)] = sp;
            if (WRITESOUT) sout[idx] = sp;
        }
    }
}

// ---------------- bconv v9: v6 + weights staged in LDS ----------------------
// Identical structure/values to v6; only the weight source changes: 9KB LDS
// block staged once (all 256 threads, single barrier), per-ic reads become
// uniform-address ds_read broadcasts (no scalar-cache thrash).
template <bool HASRES, bool WRITESOUT>
__global__ __launch_bounds__(256, 4) void bconv_v9(
    const float* __restrict__ pin,    // padded [16][64][30][30]
    const float* __restrict__ wt,     // [16 ocg][64 ic][9][4]
    float* __restrict__ mem,
    float* __restrict__ sout,
    const float* __restrict__ resid,
    float* __restrict__ psout)
{
    __shared__ float wlds[2304];      // 9 KB
    const int tid = threadIdx.x;
    const int yq  = blockIdx.x;
    const int ocg = blockIdx.y;       // 0..15
    const int oc0 = ocg * 4;
    const int n   = blockIdx.z;

    {   // stage weights (all threads), one barrier
        const float* wblk = wt + ocg * 2304;
#pragma unroll
        for (int k = 0; k < 9; ++k) {
            int idx = tid + k * 256;
            if (idx < 2304) wlds[idx] = wblk[idx];
        }
    }
    __syncthreads();
    if (tid >= 196) return;

    const int xx  = tid % 28;
    const int rl  = tid / 28;
    const int yy  = yq * 7 + rl;
    const float* p = pin + (size_t)n * 64 * PPLANE + yy * 30 + xx;

    float acc[4];
#pragma unroll
    for (int o = 0; o < 4; ++o) acc[o] = 0.f;

    float va[9], vb[9], vc[9], vd[9];
    BC_LD9(va, 0)
    BC_LD9(vb, 1)
#pragma clang loop unroll(disable)
    for (int ic = 0; ic < 64; ic += 4) {
        BC_LD9(vc, ic + 2)
        BC_COMP_W(va, ic, wlds)
        BC_LD9(vd, ic + 3)
        BC_COMP_W(vb, ic + 1, wlds)
        if (ic + 4 < 64) BC_LD9(va, ic + 4)
        BC_COMP_W(vc, ic + 2, wlds)
        if (ic + 5 < 64) BC_LD9(vb, ic + 5)
        BC_COMP_W(vd, ic + 3, wlds)
    }

    {
#pragma clang fp contract(off)
#pragma unroll
        for (int o = 0; o < 4; ++o) {
            size_t idx = (((size_t)n * 64 + oc0 + o) * 28 + yy) * 28 + xx;
            float m = mem[idx] * 0.8f;
            m = m + acc[o];
            if (HASRES) m = m + resid[idx];
            mem[idx] = m;
            float sp = (m > 0.5f) ? 1.f : 0.f;
            psout[((size_t)n * 64 + oc0 + o) * PPLANE + (yy + 1) * 30 + (xx + 1)] = sp;
            if (WRITESOUT) sout[idx] = sp;
        }
    }
}

// ---------------- feat = avgpool7x7(concat s2 of blocks 0,2,4,6) ------------
__global__ __launch_bounds__(256) void featpool_k(const float* __restrict__ s2all,
                                                  float* __restrict__ feat) {
    int i = blockIdx.x * 256 + threadIdx.x;
    if (i >= 16 * 4096) return;
    int n = i >> 12;
    int f = i & 4095;
    int c = f >> 4;
    int py = (f >> 2) & 3, px = f & 3;
    int s = c >> 6, cc = c & 63;
    const float* src = s2all + ((size_t)(2 * s) * 16 * 64 + n * 64 + cc) * PLANE28;
    float sum = 0.f;
    for (int dy = 0; dy < 7; ++dy)
        for (int dx = 0; dx < 7; ++dx)
            sum += src[(py * 7 + dy) * 28 + px * 7 + dx];
    feat[i] = sum / 49.0f;
}

// ---------------- FC: 8 lanes per (n,cls), frozen 8x512 chains --------------
__global__ __launch_bounds__(256) void fc_w8(
    const float* __restrict__ feat, const float* __restrict__ w,
    const float* __restrict__ b, float* __restrict__ fc_mem,
    float* __restrict__ out) {
    int gt = blockIdx.x * 256 + threadIdx.x;
    int g  = gt >> 3;
    int j  = gt & 7;
    if (g >= 16 * 101) return;
    int n = g / 101, cls = g % 101;
    const float* fb = feat + (size_t)n * 4096 + j * 512;
    const float* wb = w + (size_t)cls * 4096 + j * 512;
    float sub = 0.f;
    for (int k = 0; k < 512; ++k)
        sub = fmaf(fb[k], wb[k], sub);
    int lane = threadIdx.x & 63;
    int base = lane & ~7;
    float s0 = __shfl(sub, base + 0, 64);
    float s1 = __shfl(sub, base + 1, 64);
    float s2 = __shfl(sub, base + 2, 64);
    float s3 = __shfl(sub, base + 3, 64);
    float s4 = __shfl(sub, base + 4, 64);
    float s5 = __shfl(sub, base + 5, 64);
    float s6 = __shfl(sub, base + 6, 64);
    float s7 = __shfl(sub, base + 7, 64);
    if (j == 0) {
#pragma clang fp contract(off)
        float a = s0;
        a = a + s1; a = a + s2; a = a + s3;
        a = a + s4; a = a + s5; a = a + s6; a = a + s7;
        float o = a + b[cls];
        float m = fc_mem[g] * 0.8f;
        m = m + o;
        fc_mem[g] = m;
        if (m > 0.5f) out[g] += 0.125f;
    }
}

extern "C" void kernel_launch(void* const* d_in, const int* in_sizes, int n_in,
                              void* d_out, int out_size, void* d_ws, size_t ws_size,
                              hipStream_t stream) {
    const float* x   = (const float*)d_in[0];
    const float* w1  = (const float*)d_in[1];
    const float* wb1 = (const float*)d_in[2];
    const float* wb2 = (const float*)d_in[3];
    const float* fcw = (const float*)d_in[4];
    const float* fcb = (const float*)d_in[5];
    float* out = (float*)d_out;

    // ---- workspace (all fp32): zeroed state first, then scratch
    float* fws    = (float*)d_ws;
    float* c_mem  = fws;                         // 3,211,264
    float* b1m    = c_mem + NPLANE56;            // 8*802,816
    float* b2m    = b1m + 8 * NPLANE28;          // 8*802,816
    float* fc_mem = b2m + 8 * NPLANE28;          // 1,616
    float* cur0   = fc_mem + 1616;               // 802,816
    float* feat   = cur0 + NPLANE28;             // 65,536
    float* s2all  = feat + 16 * 4096;            // 8*802,816
    float* w1t    = s2all + 8 * NPLANE28;        // 62,720
    float* wb1t4  = w1t + 62720;                 // 294,912 (layer A)
    float* wb2t4  = wb1t4 + 294912;              // 294,912 (layer B)
    float* pb     = wb2t4 + 294912;              // 921,600 padded ping
    float* ps1    = pb + NPPLANE;                // 921,600 padded s1

    size_t zeroN = (size_t)NPLANE56 + 16 * NPLANE28 + 1616;
    hipMemsetAsync(c_mem, 0, zeroN * sizeof(float), stream);
    hipMemsetAsync(pb, 0, 2 * (size_t)NPPLANE * sizeof(float), stream);  // zero halos
    hipMemsetAsync(d_out, 0, 16 * 101 * sizeof(float), stream);

    transpose_w1<<<(62720 + 255) / 256, 256, 0, stream>>>(w1, w1t);
    transpose_wb4<<<(294912 + 255) / 256, 256, 0, stream>>>(wb1, wb1t4);
    transpose_wb4<<<(294912 + 255) / 256, 256, 0, stream>>>(wb2, wb2t4);

    for (int t = 0; t < 8; ++t) {
        conv1_t4<<<dim3(8, 8, 16), 256, 0, stream>>>(x, w1t, c_mem, t);
        pool1_p2<<<NPLANE28 / 256, 256, 0, stream>>>(c_mem, cur0, pb);
        for (int i = 0; i < 8; ++i) {
            const float* wA = wb1t4 + (size_t)i * 36864;
            const float* wB = wb2t4 + (size_t)i * 36864;
            float* m1 = b1m + (size_t)i * NPLANE28;
            float* m2 = b2m + (size_t)i * NPLANE28;
            float* so = s2all + (size_t)i * NPLANE28;
            const float* binres = (i == 0) ? cur0 : s2all + (size_t)(i - 1) * NPLANE28;
            // A: v9 (LDS weights) — reads padded pb, writes padded ps1
            bconv_v9<false, false><<<dim3(4, 16, 16), 256, 0, stream>>>(
                pb, wA, m1, nullptr, nullptr, ps1);
            // B: v6 (proven baseline) — reads ps1, writes normal so + padded pb
            bconv_v6<true, true><<<dim3(4, 16, 16), 256, 0, stream>>>(
                ps1, wB, m2, so, binres, pb);
        }
        featpool_k<<<16 * 4096 / 256, 256, 0, stream>>>(s2all, feat);
        fc_w8<<<(16 * 101 * 8 + 255) / 256, 256, 0, stream>>>(feat, fcw, fcb, fc_mem, out);
    }
}

// Round 19
// 12383.295 us; speedup vs baseline: 1.6624x; 1.6624x over previous
//
#include <hip/hip_runtime.h>

// ---- geometry ----
#define PLANE28   784                  // 28*28
#define NPLANE28  (16*64*PLANE28)      // 802816  [16,64,28,28]
#define NPLANE56  (16*64*56*56)        // 3211264 [16,64,56,56]
#define C1T_ROWS  61
#define C1T_S     44                   // padded row stride (4*44 % 32 == 16 -> 2-way max)
#define C1T_LOG   (C1T_ROWS*37)        // 2257 logical words
#define PPLANE    900                  // padded 30*30
#define NPPLANE   (16*64*PPLANE)       // 921600

// FROZEN SEMANTICS (validated rounds 7-11,15-18, absmax=0):
//  - conv reductions: per-ic subtotal. sub = fmaf chain over (ky outer, kx inner),
//    OOB as zero-tap fmaf no-op (zero-halo padded layout is bit-identical);
//    acc = acc + sub in ic order.
//  - membrane: m = mem*0.8f; m = m + conv; [m = m + resid;]  (contract OFF)
//  - fc: 8 x 512-term sequential fmaf chains, subtotals added in order; o = acc + b.
//  - pool sums are exact small integers (order-free), divided by 9.0f / 49.0f.
// LESSON (r14): never fully unroll a pipelined load loop (hoist->spill).
// LESSON (r15): mask removal + prefetch depth NEUTRAL.
// LESSON (r16/r17): blocks/CU below 4 loses.
// LESSON (r18): weights MUST stay s_load/SGPR — LDS weights become VGPR
// operands and spill (872MB scratch). Only unexplored winning-axis move:
// MORE blocks/CU (v10: 32 ocg x 2 oc, 8 blocks/CU, 100% occupancy).

// ---------------- weight transposes (once per launch) -----------------------
__global__ __launch_bounds__(256) void transpose_w1(const float* __restrict__ w,
                                                    float* __restrict__ wt) {
    int i = blockIdx.x * 256 + threadIdx.x;
    if (i >= 64 * 20 * 49) return;
    int oc = i / 980;
    int r  = i % 980;
    int ic = r / 49;
    int ky = (r % 49) / 7;
    int kx = r % 7;
    wt[((ic * 7 + ky) * 7 + kx) * 64 + oc] = w[i];
}

// [8][64oc][64ic][3ky][3kx] -> [8][16 ocg][64 ic][9][4 oc]   (v6, layer B)
__global__ __launch_bounds__(256) void transpose_wb4(const float* __restrict__ w,
                                                     float* __restrict__ wt) {
    int i = blockIdx.x * 256 + threadIdx.x;
    if (i >= 8 * 64 * 64 * 9) return;
    int l  = i / 36864;
    int r  = i % 36864;
    int oc = r / 576;
    int r2 = r % 576;
    int ic = r2 / 9;
    int t9 = r2 % 9;
    wt[l * 36864 + (oc >> 2) * 2304 + ic * 36 + t9 * 4 + (oc & 3)] = w[i];
}

// [8][64oc][64ic][3ky][3kx] -> [8][32 ocg][64 ic][9][2 oc]   (v10, layer A)
__global__ __launch_bounds__(256) void transpose_wb2(const float* __restrict__ w,
                                                     float* __restrict__ wt) {
    int i = blockIdx.x * 256 + threadIdx.x;
    if (i >= 8 * 64 * 64 * 9) return;
    int l  = i / 36864;
    int r  = i % 36864;
    int oc = r / 576;
    int r2 = r % 576;
    int ic = r2 / 9;
    int t9 = r2 % 9;
    wt[l * 36864 + (oc >> 1) * 1152 + ic * 18 + t9 * 2 + (oc & 1)] = w[i];
}

// ---------------- conv1 7x7 s2 p3 (20->64) + membrane, stride-44 LDS --------
__global__ __launch_bounds__(256) void conv1_t4(
    const float* __restrict__ x,    // [16,8,20,112,112]
    const float* __restrict__ wt,   // [20][7][7][64]
    float* __restrict__ c_mem,      // [16,64,56,56]
    int t)
{
    __shared__ float tile[C1T_ROWS * C1T_S];
    const int tid = threadIdx.x;
    const int bx  = blockIdx.x >> 1;
    const int yh  = blockIdx.x & 1;
    const int oc0 = blockIdx.y * 8;
    const int n   = blockIdx.z;
    const int tx  = tid & 15;
    const int ty  = tid >> 4;            // active ty<14
    const float* xin = x + ((size_t)(n * 8 + t)) * 20 * 12544;
    const int cbase = 32 * bx - 3;
    const int row0  = 56 * yh - 3;

    float acc[8][2];
#pragma unroll
    for (int o = 0; o < 8; ++o) { acc[o][0] = 0.f; acc[o][1] = 0.f; }

#pragma unroll
    for (int k = 0; k < 9; ++k) {
        int idx = tid + k * 256;
        if (idx < C1T_LOG) {
            int r = idx / 37, c = idx - r * 37;
            int ri = row0 + r, ci = cbase + c;
            float v = 0.f;
            if ((unsigned)ri < 112u && (unsigned)ci < 112u) v = xin[ri * 112 + ci];
            int cpos = (c >> 1) + ((c & 1) ? 19 : 0);
            tile[r * C1T_S + cpos] = v;
        }
    }

    for (int ic = 0; ic < 20; ++ic) {
        __syncthreads();
        float pre[9];
        if (ic + 1 < 20) {
            const float* src = xin + (ic + 1) * 12544;
#pragma unroll
            for (int k = 0; k < 9; ++k) {
                int idx = tid + k * 256;
                float v = 0.f;
                if (idx < C1T_LOG) {
                    int r = idx / 37, c = idx - r * 37;
                    int ri = row0 + r, ci = cbase + c;
                    if ((unsigned)ri < 112u && (unsigned)ci < 112u) v = src[ri * 112 + ci];
                }
                pre[k] = v;
            }
        }
        if (ty < 14) {
            float sub[8][2];
#pragma unroll
            for (int o = 0; o < 8; ++o) { sub[o][0] = 0.f; sub[o][1] = 0.f; }
            const float* wic = wt + ic * (49 * 64) + oc0;
#pragma unroll
            for (int ky = 0; ky < 7; ++ky) {     // ky OUTER (frozen order)
#pragma unroll
                for (int kx = 0; kx < 7; ++kx) { // kx INNER
                    const int koff = (kx >> 1) + ((kx & 1) ? 19 : 0);
                    const float* wp = wic + (ky * 7 + kx) * 64;
                    const float v0 = tile[(4 * ty + 0 + ky) * C1T_S + tx + koff];
                    const float v1 = tile[(4 * ty + 2 + ky) * C1T_S + tx + koff];
#pragma unroll
                    for (int o = 0; o < 8; ++o) {
                        const float wv = wp[o];
                        sub[o][0] = fmaf(v0, wv, sub[o][0]);
                        sub[o][1] = fmaf(v1, wv, sub[o][1]);
                    }
                }
            }
#pragma unroll
            for (int o = 0; o < 8; ++o) {
                acc[o][0] = acc[o][0] + sub[o][0];
                acc[o][1] = acc[o][1] + sub[o][1];
            }
        }
        __syncthreads();
        if (ic + 1 < 20) {
#pragma unroll
            for (int k = 0; k < 9; ++k) {
                int idx = tid + k * 256;
                if (idx < C1T_LOG) {
                    int r = idx / 37, c = idx - r * 37;
                    int cpos = (c >> 1) + ((c & 1) ? 19 : 0);
                    tile[r * C1T_S + cpos] = pre[k];
                }
            }
        }
    }

    const int xg = 16 * bx + tx;
    if (ty < 14 && xg < 56) {
#pragma clang fp contract(off)
#pragma unroll
        for (int o = 0; o < 8; ++o) {
#pragma unroll
            for (int d = 0; d < 2; ++d) {
                const int yg = 28 * yh + 2 * ty + d;
                size_t idx = (((size_t)n * 64 + oc0 + o) * 56 + yg) * 56 + xg;
                float m = c_mem[idx] * 0.8f;
                m = m + acc[o][d];
                c_mem[idx] = m;
            }
        }
    }
}

// ---------------- avg_pool + padded-layout write ----------------------------
__global__ __launch_bounds__(256) void pool1_p2(const float* __restrict__ c_mem,
                                                float* __restrict__ cur,
                                                float* __restrict__ pcur) {
    int i = blockIdx.x * 256 + threadIdx.x;
    if (i >= NPLANE28) return;
    int xx = i % 28, yy = (i / 28) % 28;
    int p  = i / PLANE28;
    const float* src = c_mem + (size_t)p * 3136;
    float s = 0.f;
    for (int ky = 0; ky < 3; ++ky) {
        int iy = 2 * yy - 1 + ky;
        if ((unsigned)iy >= 56u) continue;
        for (int kx = 0; kx < 3; ++kx) {
            int ix = 2 * xx - 1 + kx;
            if ((unsigned)ix < 56u)
                s += (src[iy * 56 + ix] > 0.5f) ? 1.f : 0.f;
        }
    }
    float v = s / 9.0f;
    cur[i] = v;
    pcur[(size_t)p * PPLANE + (yy + 1) * 30 + (xx + 1)] = v;
}

// ---------------- common tap macro (frozen chain) ---------------------------
#define BC_LD9(V, IC)                                        \
    {                                                        \
        const float* q = p + (size_t)(IC) * PPLANE;          \
        V[0] = q[0];  V[1] = q[1];  V[2] = q[2];             \
        V[3] = q[30]; V[4] = q[31]; V[5] = q[32];            \
        V[6] = q[60]; V[7] = q[61]; V[8] = q[62];            \
    }

#define BC_COMP4(V, IC)                                      \
    {                                                        \
        const float* wic = wblk + (IC) * 36;                 \
        float sub[4];                                        \
        sub[0] = 0.f; sub[1] = 0.f; sub[2] = 0.f; sub[3] = 0.f; \
        _Pragma("unroll")                                    \
        for (int t9 = 0; t9 < 9; ++t9) {                     \
            const float* wp = wic + t9 * 4;                  \
            _Pragma("unroll")                                \
            for (int o = 0; o < 4; ++o)                      \
                sub[o] = fmaf(V[t9], wp[o], sub[o]);         \
        }                                                    \
        _Pragma("unroll")                                    \
        for (int o = 0; o < 4; ++o) acc[o] = acc[o] + sub[o];\
    }

#define BC_COMP2(V, IC)                                      \
    {                                                        \
        const float* wic = wblk + (IC) * 18;                 \
        float sub[2];                                        \
        sub[0] = 0.f; sub[1] = 0.f;                          \
        _Pragma("unroll")                                    \
        for (int t9 = 0; t9 < 9; ++t9) {                     \
            const float* wp = wic + t9 * 2;                  \
            sub[0] = fmaf(V[t9], wp[0], sub[0]);             \
            sub[1] = fmaf(V[t9], wp[1], sub[1]);             \
        }                                                    \
        acc[0] = acc[0] + sub[0];                            \
        acc[1] = acc[1] + sub[1];                            \
    }

// ---------------- bconv v6 (proven: 16 ocg, 4 oc, s_load weights) -----------
template <bool HASRES, bool WRITESOUT>
__global__ __launch_bounds__(256, 4) void bconv_v6(
    const float* __restrict__ pin,    // padded [16][64][30][30]
    const float* __restrict__ wt,     // [16 ocg][64 ic][9][4]
    float* __restrict__ mem,
    float* __restrict__ sout,
    const float* __restrict__ resid,
    float* __restrict__ psout)
{
    const int tid = threadIdx.x;
    if (tid >= 196) return;
    const int yq  = blockIdx.x;
    const int ocg = blockIdx.y;       // 0..15
    const int oc0 = ocg * 4;
    const int n   = blockIdx.z;
    const int xx  = tid % 28;
    const int rl  = tid / 28;
    const int yy  = yq * 7 + rl;

    const float* p = pin + (size_t)n * 64 * PPLANE + yy * 30 + xx;
    const float* wblk = wt + ocg * 2304;

    float acc[4];
#pragma unroll
    for (int o = 0; o < 4; ++o) acc[o] = 0.f;

    float va[9], vb[9], vc[9], vd[9];
    BC_LD9(va, 0)
    BC_LD9(vb, 1)
#pragma clang loop unroll(disable)
    for (int ic = 0; ic < 64; ic += 4) {
        BC_LD9(vc, ic + 2)
        BC_COMP4(va, ic)
        BC_LD9(vd, ic + 3)
        BC_COMP4(vb, ic + 1)
        if (ic + 4 < 64) BC_LD9(va, ic + 4)
        BC_COMP4(vc, ic + 2)
        if (ic + 5 < 64) BC_LD9(vb, ic + 5)
        BC_COMP4(vd, ic + 3)
    }

    {
#pragma clang fp contract(off)
#pragma unroll
        for (int o = 0; o < 4; ++o) {
            size_t idx = (((size_t)n * 64 + oc0 + o) * 28 + yy) * 28 + xx;
            float m = mem[idx] * 0.8f;
            m = m + acc[o];
            if (HASRES) m = m + resid[idx];
            mem[idx] = m;
            float sp = (m > 0.5f) ? 1.f : 0.f;
            psout[((size_t)n * 64 + oc0 + o) * PPLANE + (yy + 1) * 30 + (xx + 1)] = sp;
            if (WRITESOUT) sout[idx] = sp;
        }
    }
}

// ---------------- bconv v10: 32 ocg x 2 oc, 8 blocks/CU (100% occupancy) ----
template <bool HASRES, bool WRITESOUT>
__global__ __launch_bounds__(256, 8) void bconv_v10(
    const float* __restrict__ pin,    // padded [16][64][30][30]
    const float* __restrict__ wt,     // [32 ocg][64 ic][9][2]
    float* __restrict__ mem,
    float* __restrict__ sout,
    const float* __restrict__ resid,
    float* __restrict__ psout)
{
    const int tid = threadIdx.x;
    if (tid >= 196) return;
    const int yq  = blockIdx.x;
    const int ocg = blockIdx.y;       // 0..31
    const int oc0 = ocg * 2;
    const int n   = blockIdx.z;
    const int xx  = tid % 28;
    const int rl  = tid / 28;
    const int yy  = yq * 7 + rl;

    const float* p = pin + (size_t)n * 64 * PPLANE + yy * 30 + xx;
    const float* wblk = wt + ocg * 1152;

    float acc[2];
    acc[0] = 0.f; acc[1] = 0.f;

    float va[9], vb[9], vc[9], vd[9];
    BC_LD9(va, 0)
    BC_LD9(vb, 1)
#pragma clang loop unroll(disable)
    for (int ic = 0; ic < 64; ic += 4) {
        BC_LD9(vc, ic + 2)
        BC_COMP2(va, ic)
        BC_LD9(vd, ic + 3)
        BC_COMP2(vb, ic + 1)
        if (ic + 4 < 64) BC_LD9(va, ic + 4)
        BC_COMP2(vc, ic + 2)
        if (ic + 5 < 64) BC_LD9(vb, ic + 5)
        BC_COMP2(vd, ic + 3)
    }

    {
#pragma clang fp contract(off)
#pragma unroll
        for (int o = 0; o < 2; ++o) {
            size_t idx = (((size_t)n * 64 + oc0 + o) * 28 + yy) * 28 + xx;
            float m = mem[idx] * 0.8f;
            m = m + acc[o];
            if (HASRES) m = m + resid[idx];
            mem[idx] = m;
            float sp = (m > 0.5f) ? 1.f : 0.f;
            psout[((size_t)n * 64 + oc0 + o) * PPLANE + (yy + 1) * 30 + (xx + 1)] = sp;
            if (WRITESOUT) sout[idx] = sp;
        }
    }
}

// ---------------- feat = avgpool7x7(concat s2 of blocks 0,2,4,6) ------------
__global__ __launch_bounds__(256) void featpool_k(const float* __restrict__ s2all,
                                                  float* __restrict__ feat) {
    int i = blockIdx.x * 256 + threadIdx.x;
    if (i >= 16 * 4096) return;
    int n = i >> 12;
    int f = i & 4095;
    int c = f >> 4;
    int py = (f >> 2) & 3, px = f & 3;
    int s = c >> 6, cc = c & 63;
    const float* src = s2all + ((size_t)(2 * s) * 16 * 64 + n * 64 + cc) * PLANE28;
    float sum = 0.f;
    for (int dy = 0; dy < 7; ++dy)
        for (int dx = 0; dx < 7; ++dx)
            sum += src[(py * 7 + dy) * 28 + px * 7 + dx];
    feat[i] = sum / 49.0f;
}

// ---------------- FC: 8 lanes per (n,cls), frozen 8x512 chains --------------
__global__ __launch_bounds__(256) void fc_w8(
    const float* __restrict__ feat, const float* __restrict__ w,
    const float* __restrict__ b, float* __restrict__ fc_mem,
    float* __restrict__ out) {
    int gt = blockIdx.x * 256 + threadIdx.x;
    int g  = gt >> 3;
    int j  = gt & 7;
    if (g >= 16 * 101) return;
    int n = g / 101, cls = g % 101;
    const float* fb = feat + (size_t)n * 4096 + j * 512;
    const float* wb = w + (size_t)cls * 4096 + j * 512;
    float sub = 0.f;
    for (int k = 0; k < 512; ++k)
        sub = fmaf(fb[k], wb[k], sub);
    int lane = threadIdx.x & 63;
    int base = lane & ~7;
    float s0 = __shfl(sub, base + 0, 64);
    float s1 = __shfl(sub, base + 1, 64);
    float s2 = __shfl(sub, base + 2, 64);
    float s3 = __shfl(sub, base + 3, 64);
    float s4 = __shfl(sub, base + 4, 64);
    float s5 = __shfl(sub, base + 5, 64);
    float s6 = __shfl(sub, base + 6, 64);
    float s7 = __shfl(sub, base + 7, 64);
    if (j == 0) {
#pragma clang fp contract(off)
        float a = s0;
        a = a + s1; a = a + s2; a = a + s3;
        a = a + s4; a = a + s5; a = a + s6; a = a + s7;
        float o = a + b[cls];
        float m = fc_mem[g] * 0.8f;
        m = m + o;
        fc_mem[g] = m;
        if (m > 0.5f) out[g] += 0.125f;
    }
}

extern "C" void kernel_launch(void* const* d_in, const int* in_sizes, int n_in,
                              void* d_out, int out_size, void* d_ws, size_t ws_size,
                              hipStream_t stream) {
    const float* x   = (const float*)d_in[0];
    const float* w1  = (const float*)d_in[1];
    const float* wb1 = (const float*)d_in[2];
    const float* wb2 = (const float*)d_in[3];
    const float* fcw = (const float*)d_in[4];
    const float* fcb = (const float*)d_in[5];
    float* out = (float*)d_out;

    // ---- workspace (all fp32): zeroed state first, then scratch
    float* fws    = (float*)d_ws;
    float* c_mem  = fws;                         // 3,211,264
    float* b1m    = c_mem + NPLANE56;            // 8*802,816
    float* b2m    = b1m + 8 * NPLANE28;          // 8*802,816
    float* fc_mem = b2m + 8 * NPLANE28;          // 1,616
    float* cur0   = fc_mem + 1616;               // 802,816
    float* feat   = cur0 + NPLANE28;             // 65,536
    float* s2all  = feat + 16 * 4096;            // 8*802,816
    float* w1t    = s2all + 8 * NPLANE28;        // 62,720
    float* wb1t2  = w1t + 62720;                 // 294,912 (v10 layout, layer A)
    float* wb2t4  = wb1t2 + 294912;              // 294,912 (v6 layout, layer B)
    float* pb     = wb2t4 + 294912;              // 921,600 padded ping
    float* ps1    = pb + NPPLANE;                // 921,600 padded s1

    size_t zeroN = (size_t)NPLANE56 + 16 * NPLANE28 + 1616;
    hipMemsetAsync(c_mem, 0, zeroN * sizeof(float), stream);
    hipMemsetAsync(pb, 0, 2 * (size_t)NPPLANE * sizeof(float), stream);  // zero halos
    hipMemsetAsync(d_out, 0, 16 * 101 * sizeof(float), stream);

    transpose_w1<<<(62720 + 255) / 256, 256, 0, stream>>>(w1, w1t);
    transpose_wb2<<<(294912 + 255) / 256, 256, 0, stream>>>(wb1, wb1t2);
    transpose_wb4<<<(294912 + 255) / 256, 256, 0, stream>>>(wb2, wb2t4);

    for (int t = 0; t < 8; ++t) {
        conv1_t4<<<dim3(8, 8, 16), 256, 0, stream>>>(x, w1t, c_mem, t);
        pool1_p2<<<NPLANE28 / 256, 256, 0, stream>>>(c_mem, cur0, pb);
        for (int i = 0; i < 8; ++i) {
            const float* wA = wb1t2 + (size_t)i * 36864;
            const float* wB = wb2t4 + (size_t)i * 36864;
            float* m1 = b1m + (size_t)i * NPLANE28;
            float* m2 = b2m + (size_t)i * NPLANE28;
            float* so = s2all + (size_t)i * NPLANE28;
            const float* binres = (i == 0) ? cur0 : s2all + (size_t)(i - 1) * NPLANE28;
            // A: v10 (32 ocg, 8 blocks/CU) — reads padded pb, writes padded ps1
            bconv_v10<false, false><<<dim3(4, 32, 16), 256, 0, stream>>>(
                pb, wA, m1, nullptr, nullptr, ps1);
            // B: v6 (proven baseline) — reads ps1, writes normal so + padded pb
            bconv_v6<true, true><<<dim3(4, 16, 16), 256, 0, stream>>>(
                ps1, wB, m2, so, binres, pb);
        }
        featpool_k<<<16 * 4096 / 256, 256, 0, stream>>>(s2all, feat);
        fc_w8<<<(16 * 101 * 8 + 255) / 256, 256, 0, stream>>>(feat, fcw, fcb, fc_mem, out);
    }
}

// Round 20
// 5235.309 us; speedup vs baseline: 3.9320x; 2.3653x over previous
//
#include <hip/hip_runtime.h>

// ---- geometry ----
#define PLANE28   784                  // 28*28
#define NPLANE28  (16*64*PLANE28)      // 802816  [16,64,28,28]
#define NPLANE56  (16*64*56*56)        // 3211264 [16,64,56,56]
#define C1T_ROWS  61
#define C1T_S     44                   // padded row stride (176 mod 32 = 16 -> 2-way max = free)
#define C1T_LOG   (C1T_ROWS*37)        // 2257 logical words
#define PPLANE    900                  // padded 30*30
#define NPPLANE   (16*64*PPLANE)       // 921600

// FROZEN SEMANTICS (validated rounds 7-11,15-19, absmax=0):
//  - conv reductions: per-ic subtotal. sub = fmaf chain over (ky outer, kx inner),
//    OOB as zero-tap fmaf no-op (zero-halo padded layout is bit-identical);
//    acc = acc + sub in ic order.
//  - membrane: m = mem*0.8f; m = m + conv; [m = m + resid;]  (contract OFF)
//  - fc: 8 x 512-term sequential fmaf chains, subtotals added in order; o = acc + b.
//  - pool sums are exact small integers (order-free), divided by 9.0f / 49.0f.
// LESSONS: (r14) never fully unroll pipelined load loops (hoist->spill).
// (r15) mask removal + deeper prefetch NEUTRAL. (r16/r17) fewer blocks/CU or
// LDS tap-share loses. (r18) LDS weights -> VGPR operands -> spill; weights
// must stay s_load/SGPR. (r19) launch_bounds min-waves coercion caps VGPR and
// spills rings. bconv_v6 (4oc, s_load W, depth-2 named rings, natural
// occupancy) is the undefeated config -> consolidate.

// ---------------- weight transposes (once per launch) -----------------------
__global__ __launch_bounds__(256) void transpose_w1(const float* __restrict__ w,
                                                    float* __restrict__ wt) {
    int i = blockIdx.x * 256 + threadIdx.x;
    if (i >= 64 * 20 * 49) return;
    int oc = i / 980;
    int r  = i % 980;
    int ic = r / 49;
    int ky = (r % 49) / 7;
    int kx = r % 7;
    wt[((ic * 7 + ky) * 7 + kx) * 64 + oc] = w[i];
}

// [8][64oc][64ic][3ky][3kx] -> [8][16 ocg][64 ic][9][4 oc]
__global__ __launch_bounds__(256) void transpose_wb4(const float* __restrict__ w,
                                                     float* __restrict__ wt) {
    int i = blockIdx.x * 256 + threadIdx.x;
    if (i >= 8 * 64 * 64 * 9) return;
    int l  = i / 36864;
    int r  = i % 36864;
    int oc = r / 576;
    int r2 = r % 576;
    int ic = r2 / 9;
    int t9 = r2 % 9;
    wt[l * 36864 + (oc >> 2) * 2304 + ic * 36 + t9 * 4 + (oc & 3)] = w[i];
}

// ---------------- conv1 7x7 s2 p3 (20->64) + membrane, stride-44 LDS --------
__global__ __launch_bounds__(256) void conv1_t4(
    const float* __restrict__ x,    // [16,8,20,112,112]
    const float* __restrict__ wt,   // [20][7][7][64]
    float* __restrict__ c_mem,      // [16,64,56,56]
    int t)
{
    __shared__ float tile[C1T_ROWS * C1T_S];
    const int tid = threadIdx.x;
    const int bx  = blockIdx.x >> 1;
    const int yh  = blockIdx.x & 1;
    const int oc0 = blockIdx.y * 8;
    const int n   = blockIdx.z;
    const int tx  = tid & 15;
    const int ty  = tid >> 4;            // active ty<14
    const float* xin = x + ((size_t)(n * 8 + t)) * 20 * 12544;
    const int cbase = 32 * bx - 3;
    const int row0  = 56 * yh - 3;

    float acc[8][2];
#pragma unroll
    for (int o = 0; o < 8; ++o) { acc[o][0] = 0.f; acc[o][1] = 0.f; }

#pragma unroll
    for (int k = 0; k < 9; ++k) {
        int idx = tid + k * 256;
        if (idx < C1T_LOG) {
            int r = idx / 37, c = idx - r * 37;
            int ri = row0 + r, ci = cbase + c;
            float v = 0.f;
            if ((unsigned)ri < 112u && (unsigned)ci < 112u) v = xin[ri * 112 + ci];
            int cpos = (c >> 1) + ((c & 1) ? 19 : 0);
            tile[r * C1T_S + cpos] = v;
        }
    }

    for (int ic = 0; ic < 20; ++ic) {
        __syncthreads();
        float pre[9];
        if (ic + 1 < 20) {
            const float* src = xin + (ic + 1) * 12544;
#pragma unroll
            for (int k = 0; k < 9; ++k) {
                int idx = tid + k * 256;
                float v = 0.f;
                if (idx < C1T_LOG) {
                    int r = idx / 37, c = idx - r * 37;
                    int ri = row0 + r, ci = cbase + c;
                    if ((unsigned)ri < 112u && (unsigned)ci < 112u) v = src[ri * 112 + ci];
                }
                pre[k] = v;
            }
        }
        if (ty < 14) {
            float sub[8][2];
#pragma unroll
            for (int o = 0; o < 8; ++o) { sub[o][0] = 0.f; sub[o][1] = 0.f; }
            const float* wic = wt + ic * (49 * 64) + oc0;
#pragma unroll
            for (int ky = 0; ky < 7; ++ky) {     // ky OUTER (frozen order)
#pragma unroll
                for (int kx = 0; kx < 7; ++kx) { // kx INNER
                    const int koff = (kx >> 1) + ((kx & 1) ? 19 : 0);
                    const float* wp = wic + (ky * 7 + kx) * 64;
                    const float v0 = tile[(4 * ty + 0 + ky) * C1T_S + tx + koff];
                    const float v1 = tile[(4 * ty + 2 + ky) * C1T_S + tx + koff];
#pragma unroll
                    for (int o = 0; o < 8; ++o) {
                        const float wv = wp[o];
                        sub[o][0] = fmaf(v0, wv, sub[o][0]);
                        sub[o][1] = fmaf(v1, wv, sub[o][1]);
                    }
                }
            }
#pragma unroll
            for (int o = 0; o < 8; ++o) {
                acc[o][0] = acc[o][0] + sub[o][0];
                acc[o][1] = acc[o][1] + sub[o][1];
            }
        }
        __syncthreads();
        if (ic + 1 < 20) {
#pragma unroll
            for (int k = 0; k < 9; ++k) {
                int idx = tid + k * 256;
                if (idx < C1T_LOG) {
                    int r = idx / 37, c = idx - r * 37;
                    int cpos = (c >> 1) + ((c & 1) ? 19 : 0);
                    tile[r * C1T_S + cpos] = pre[k];
                }
            }
        }
    }

    const int xg = 16 * bx + tx;
    if (ty < 14 && xg < 56) {
#pragma clang fp contract(off)
#pragma unroll
        for (int o = 0; o < 8; ++o) {
#pragma unroll
            for (int d = 0; d < 2; ++d) {
                const int yg = 28 * yh + 2 * ty + d;
                size_t idx = (((size_t)n * 64 + oc0 + o) * 56 + yg) * 56 + xg;
                float m = c_mem[idx] * 0.8f;
                m = m + acc[o][d];
                c_mem[idx] = m;
            }
        }
    }
}

// ---------------- avg_pool + padded-layout write ----------------------------
__global__ __launch_bounds__(256) void pool1_p2(const float* __restrict__ c_mem,
                                                float* __restrict__ cur,
                                                float* __restrict__ pcur) {
    int i = blockIdx.x * 256 + threadIdx.x;
    if (i >= NPLANE28) return;
    int xx = i % 28, yy = (i / 28) % 28;
    int p  = i / PLANE28;
    const float* src = c_mem + (size_t)p * 3136;
    float s = 0.f;
    for (int ky = 0; ky < 3; ++ky) {
        int iy = 2 * yy - 1 + ky;
        if ((unsigned)iy >= 56u) continue;
        for (int kx = 0; kx < 3; ++kx) {
            int ix = 2 * xx - 1 + kx;
            if ((unsigned)ix < 56u)
                s += (src[iy * 56 + ix] > 0.5f) ? 1.f : 0.f;
        }
    }
    float v = s / 9.0f;
    cur[i] = v;
    pcur[(size_t)p * PPLANE + (yy + 1) * 30 + (xx + 1)] = v;
}

// ---------------- common tap macro (frozen chain) ---------------------------
#define BC_LD9(V, IC)                                        \
    {                                                        \
        const float* q = p + (size_t)(IC) * PPLANE;          \
        V[0] = q[0];  V[1] = q[1];  V[2] = q[2];             \
        V[3] = q[30]; V[4] = q[31]; V[5] = q[32];            \
        V[6] = q[60]; V[7] = q[61]; V[8] = q[62];            \
    }

#define BC_COMP4(V, IC)                                      \
    {                                                        \
        const float* wic = wblk + (IC) * 36;                 \
        float sub[4];                                        \
        sub[0] = 0.f; sub[1] = 0.f; sub[2] = 0.f; sub[3] = 0.f; \
        _Pragma("unroll")                                    \
        for (int t9 = 0; t9 < 9; ++t9) {                     \
            const float* wp = wic + t9 * 4;                  \
            _Pragma("unroll")                                \
            for (int o = 0; o < 4; ++o)                      \
                sub[o] = fmaf(V[t9], wp[o], sub[o]);         \
        }                                                    \
        _Pragma("unroll")                                    \
        for (int o = 0; o < 4; ++o) acc[o] = acc[o] + sub[o];\
    }

// ---------------- bconv v6 (proven: 16 ocg, 4 oc, s_load weights) -----------
template <bool HASRES, bool WRITESOUT>
__global__ __launch_bounds__(256, 4) void bconv_v6(
    const float* __restrict__ pin,    // padded [16][64][30][30]
    const float* __restrict__ wt,     // [16 ocg][64 ic][9][4]
    float* __restrict__ mem,
    float* __restrict__ sout,
    const float* __restrict__ resid,
    float* __restrict__ psout)
{
    const int tid = threadIdx.x;
    if (tid >= 196) return;
    const int yq  = blockIdx.x;
    const int ocg = blockIdx.y;       // 0..15
    const int oc0 = ocg * 4;
    const int n   = blockIdx.z;
    const int xx  = tid % 28;
    const int rl  = tid / 28;
    const int yy  = yq * 7 + rl;

    const float* p = pin + (size_t)n * 64 * PPLANE + yy * 30 + xx;
    const float* wblk = wt + ocg * 2304;

    float acc[4];
#pragma unroll
    for (int o = 0; o < 4; ++o) acc[o] = 0.f;

    float va[9], vb[9], vc[9], vd[9];
    BC_LD9(va, 0)
    BC_LD9(vb, 1)
#pragma clang loop unroll(disable)
    for (int ic = 0; ic < 64; ic += 4) {
        BC_LD9(vc, ic + 2)
        BC_COMP4(va, ic)
        BC_LD9(vd, ic + 3)
        BC_COMP4(vb, ic + 1)
        if (ic + 4 < 64) BC_LD9(va, ic + 4)
        BC_COMP4(vc, ic + 2)
        if (ic + 5 < 64) BC_LD9(vb, ic + 5)
        BC_COMP4(vd, ic + 3)
    }

    {
#pragma clang fp contract(off)
#pragma unroll
        for (int o = 0; o < 4; ++o) {
            size_t idx = (((size_t)n * 64 + oc0 + o) * 28 + yy) * 28 + xx;
            float m = mem[idx] * 0.8f;
            m = m + acc[o];
            if (HASRES) m = m + resid[idx];
            mem[idx] = m;
            float sp = (m > 0.5f) ? 1.f : 0.f;
            psout[((size_t)n * 64 + oc0 + o) * PPLANE + (yy + 1) * 30 + (xx + 1)] = sp;
            if (WRITESOUT) sout[idx] = sp;
        }
    }
}

// ---------------- feat = avgpool7x7(concat s2 of blocks 0,2,4,6) ------------
__global__ __launch_bounds__(256) void featpool_k(const float* __restrict__ s2all,
                                                  float* __restrict__ feat) {
    int i = blockIdx.x * 256 + threadIdx.x;
    if (i >= 16 * 4096) return;
    int n = i >> 12;
    int f = i & 4095;
    int c = f >> 4;
    int py = (f >> 2) & 3, px = f & 3;
    int s = c >> 6, cc = c & 63;
    const float* src = s2all + ((size_t)(2 * s) * 16 * 64 + n * 64 + cc) * PLANE28;
    float sum = 0.f;
    for (int dy = 0; dy < 7; ++dy)
        for (int dx = 0; dx < 7; ++dx)
            sum += src[(py * 7 + dy) * 28 + px * 7 + dx];
    feat[i] = sum / 49.0f;
}

// ---------------- FC: 8 lanes per (n,cls), frozen 8x512 chains --------------
__global__ __launch_bounds__(256) void fc_w8(
    const float* __restrict__ feat, const float* __restrict__ w,
    const float* __restrict__ b, float* __restrict__ fc_mem,
    float* __restrict__ out) {
    int gt = blockIdx.x * 256 + threadIdx.x;
    int g  = gt >> 3;
    int j  = gt & 7;
    if (g >= 16 * 101) return;
    int n = g / 101, cls = g % 101;
    const float* fb = feat + (size_t)n * 4096 + j * 512;
    const float* wb = w + (size_t)cls * 4096 + j * 512;
    float sub = 0.f;
    for (int k = 0; k < 512; ++k)
        sub = fmaf(fb[k], wb[k], sub);
    int lane = threadIdx.x & 63;
    int base = lane & ~7;
    float s0 = __shfl(sub, base + 0, 64);
    float s1 = __shfl(sub, base + 1, 64);
    float s2 = __shfl(sub, base + 2, 64);
    float s3 = __shfl(sub, base + 3, 64);
    float s4 = __shfl(sub, base + 4, 64);
    float s5 = __shfl(sub, base + 5, 64);
    float s6 = __shfl(sub, base + 6, 64);
    float s7 = __shfl(sub, base + 7, 64);
    if (j == 0) {
#pragma clang fp contract(off)
        float a = s0;
        a = a + s1; a = a + s2; a = a + s3;
        a = a + s4; a = a + s5; a = a + s6; a = a + s7;
        float o = a + b[cls];
        float m = fc_mem[g] * 0.8f;
        m = m + o;
        fc_mem[g] = m;
        if (m > 0.5f) out[g] += 0.125f;
    }
}

extern "C" void kernel_launch(void* const* d_in, const int* in_sizes, int n_in,
                              void* d_out, int out_size, void* d_ws, size_t ws_size,
                              hipStream_t stream) {
    const float* x   = (const float*)d_in[0];
    const float* w1  = (const float*)d_in[1];
    const float* wb1 = (const float*)d_in[2];
    const float* wb2 = (const float*)d_in[3];
    const float* fcw = (const float*)d_in[4];
    const float* fcb = (const float*)d_in[5];
    float* out = (float*)d_out;

    // ---- workspace (all fp32): zeroed state first, then scratch
    float* fws    = (float*)d_ws;
    float* c_mem  = fws;                         // 3,211,264
    float* b1m    = c_mem + NPLANE56;            // 8*802,816
    float* b2m    = b1m + 8 * NPLANE28;          // 8*802,816
    float* fc_mem = b2m + 8 * NPLANE28;          // 1,616
    float* cur0   = fc_mem + 1616;               // 802,816
    float* feat   = cur0 + NPLANE28;             // 65,536
    float* s2all  = feat + 16 * 4096;            // 8*802,816
    float* w1t    = s2all + 8 * NPLANE28;        // 62,720
    float* wb1t4  = w1t + 62720;                 // 294,912 (layer A)
    float* wb2t4  = wb1t4 + 294912;              // 294,912 (layer B)
    float* pb     = wb2t4 + 294912;              // 921,600 padded ping
    float* ps1    = pb + NPPLANE;                // 921,600 padded s1

    size_t zeroN = (size_t)NPLANE56 + 16 * NPLANE28 + 1616;
    hipMemsetAsync(c_mem, 0, zeroN * sizeof(float), stream);
    hipMemsetAsync(pb, 0, 2 * (size_t)NPPLANE * sizeof(float), stream);  // zero halos
    hipMemsetAsync(d_out, 0, 16 * 101 * sizeof(float), stream);

    transpose_w1<<<(62720 + 255) / 256, 256, 0, stream>>>(w1, w1t);
    transpose_wb4<<<(294912 + 255) / 256, 256, 0, stream>>>(wb1, wb1t4);
    transpose_wb4<<<(294912 + 255) / 256, 256, 0, stream>>>(wb2, wb2t4);

    for (int t = 0; t < 8; ++t) {
        conv1_t4<<<dim3(8, 8, 16), 256, 0, stream>>>(x, w1t, c_mem, t);
        pool1_p2<<<NPLANE28 / 256, 256, 0, stream>>>(c_mem, cur0, pb);
        for (int i = 0; i < 8; ++i) {
            const float* wA = wb1t4 + (size_t)i * 36864;
            const float* wB = wb2t4 + (size_t)i * 36864;
            float* m1 = b1m + (size_t)i * NPLANE28;
            float* m2 = b2m + (size_t)i * NPLANE28;
            float* so = s2all + (size_t)i * NPLANE28;
            const float* binres = (i == 0) ? cur0 : s2all + (size_t)(i - 1) * NPLANE28;
            // A: reads padded pb, writes padded ps1
            bconv_v6<false, false><<<dim3(4, 16, 16), 256, 0, stream>>>(
                pb, wA, m1, nullptr, nullptr, ps1);
            // B: reads padded ps1, residual normal, writes normal so + padded pb
            bconv_v6<true, true><<<dim3(4, 16, 16), 256, 0, stream>>>(
                ps1, wB, m2, so, binres, pb);
        }
        featpool_k<<<16 * 4096 / 256, 256, 0, stream>>>(s2all, feat);
        fc_w8<<<(16 * 101 * 8 + 255) / 256, 256, 0, stream>>>(feat, fcw, fcb, fc_mem, out);
    }
}